// Round 9
// baseline (196.864 us; speedup 1.0000x reference)
//
#include <hip/hip_runtime.h>
#include <stdint.h>

#define NB 16
#define NN 25200
#define NCLS 80
#define NROW 85
#define KPRE 1000
#define MAXDET 300
#define CONF_T 0.25f
#define IOU_T 0.45f
#define CCAP 2048  // candidate capacity per image

typedef unsigned long long u64;
typedef unsigned int u32;
typedef unsigned short u16;
typedef unsigned char u8;

// Descending-order sortable key: higher score -> smaller key; ties by index.
__device__ __forceinline__ u32 desc_key(float s) {
  u32 u = __float_as_uint(s);
  u = (u & 0x80000000u) ? ~u : (u | 0x80000000u);
  return ~u;
}
__device__ __forceinline__ float inv_key(u32 k) {
  u32 u = ~k;
  u32 o = (u & 0x80000000u) ? (u & 0x7fffffffu) : ~u;
  return __uint_as_float(o);
}

// ---------------- Kernel 0: zero hist region ----------------
__global__ __launch_bounds__(1024) void k_zero(u32* __restrict__ z, int total) {
  int i = blockIdx.x * 1024 + threadIdx.x;
  if (i < total) z[i] = 0;
}

// ------- Kernel 1: decode + fused 12-bit (LDS) & 16-bit (global) hist -------
__global__ __launch_bounds__(256) void k_decode(
    const float* __restrict__ pred, float* __restrict__ scores,
    int* __restrict__ clsArr, float4* __restrict__ boxes,
    u32* __restrict__ h12, u32* __restrict__ h16) {
  __shared__ __align__(16) float lds[4][1360];
  __shared__ u32 h[4096];
  const int tid = threadIdx.x;
  const int wid = tid >> 6, lane = tid & 63;
  const int q = lane & 3, rl = lane >> 2;
  const int img = blockIdx.y;
  for (int t = tid; t < 4096; t += 256) h[t] = 0;
  float* L = lds[wid];
  const float* base = pred + (size_t)img * NN * NROW;
  const int waveRow0 = blockIdx.x * 256 + wid * 64;
  const int IMGF = NN * NROW;
  __syncthreads();
  for (int c = 0; c < 4; ++c) {
    const int row0 = waveRow0 + c * 16;
    const int fbase = row0 * NROW;
#pragma unroll
    for (int k = 0; k < 5; ++k) {
      int off = k * 256 + lane * 4;
      int src = (fbase + off + 4 <= IMGF) ? (fbase + off) : 0;
      float4 v;
      __builtin_memcpy(&v, base + src, 16);
      *(float4*)(L + off) = v;
    }
    if (lane < 20) {
      int off = 1280 + lane * 4;
      int src = (fbase + off + 4 <= IMGF) ? (fbase + off) : 0;
      float4 v;
      __builtin_memcpy(&v, base + src, 16);
      *(float4*)(L + off) = v;
    }
    __syncthreads();
    const int row = row0 + rl;
    const bool rowOK = (row < NN);
    const float* R = L + rl * 85;
    float obj = R[4];
    float best = -1.0f;
    int bj = 0;
    const int j0 = q * 20;
#pragma unroll
    for (int jj = 0; jj < 20; ++jj) {
      float v = __fmul_rn(R[5 + j0 + jj], obj);
      if (v > best) { best = v; bj = j0 + jj; }
    }
#pragma unroll
    for (int d = 1; d < 4; d <<= 1) {
      float b2 = __shfl_xor(best, d, 64);
      int j2 = __shfl_xor(bj, d, 64);
      if (b2 > best || (b2 == best && j2 < bj)) { best = b2; bj = j2; }
    }
    bool valid = (best > CONF_T);
    if (q == 0 && rowOK) {
      if (valid) {
        u32 k = desc_key(best);
        atomicAdd(&h[k >> 20], 1u);
        atomicAdd(&h16[(size_t)img * 65536 + (k >> 16)], 1u);
      }
      int gid = img * NN + row;
      float x = R[0], y = R[1], w = R[2], hgt = R[3];
      float hx = __fmul_rn(w, 0.5f), hy = __fmul_rn(hgt, 0.5f);
      float4 bx;
      bx.x = __fsub_rn(x, hx);
      bx.y = __fsub_rn(y, hy);
      bx.z = __fadd_rn(x, hx);
      bx.w = __fadd_rn(y, hy);
      scores[gid] = valid ? best : -1.0f;
      clsArr[gid] = bj;
      boxes[gid] = bx;
    }
    __syncthreads();
  }
  for (int t = tid; t < 4096; t += 256) {
    u32 v = h[t];
    if (v) atomicAdd(&h12[img * 4096 + t], v);
  }
}

// ------- Kernel 2: distributed gather (13 blocks/image) -------
// Each block recomputes the exact 16-bit threshold from h12+h16 (parallel
// redundancy), then gathers candidates from its 2048-score slice.
__global__ __launch_bounds__(1024) void k_gather(
    const float* __restrict__ scores, const u32* __restrict__ h12,
    const u32* __restrict__ h16, u32* __restrict__ candCnt,
    u64* __restrict__ candKey, u32* __restrict__ thrG) {
  const int img = blockIdx.y, sub = blockIdx.x;
  const int tid = threadIdx.x, lane = tid & 63;
  __shared__ u32 wt[16];
  __shared__ u32 sB, sKr, sThr, sTake;
  if (tid == 0) sB = 0xFFFFFFFFu;

  // A: 12-bit bucket of the 1000th valid key
  uint4 hv = *(const uint4*)(h12 + (size_t)img * 4096 + tid * 4);
  u32 s4 = hv.x + hv.y + hv.z + hv.w;
  u32 incl = s4;
#pragma unroll
  for (int d = 1; d < 64; d <<= 1) {
    u32 o = __shfl_up(incl, (unsigned)d, 64);
    if (lane >= d) incl += o;
  }
  if (lane == 63) wt[tid >> 6] = incl;
  __syncthreads();
  {
    u32 woff = 0;
    int w = tid >> 6;
    for (int x = 0; x < w; ++x) woff += wt[x];
    u32 P = woff + incl - s4;
    if (P < KPRE && P + s4 >= KPRE) {
      u32 cacc = P, b = 3;
      if (cacc + hv.x >= KPRE) b = 0;
      else {
        cacc += hv.x;
        if (cacc + hv.y >= KPRE) b = 1;
        else {
          cacc += hv.y;
          if (cacc + hv.z >= KPRE) b = 2;
          else cacc += hv.z;
        }
      }
      sB = tid * 4 + b;
      sKr = KPRE - cacc;
    }
  }
  __syncthreads();
  if (sB == 0xFFFFFFFFu) {
    // fewer than KPRE valid rows: keep all valid
    if (tid == 0) { sThr = 0xFFFFu; sTake = 0x7FFFFFFFu; }
  } else if (tid < 64) {
    u32 B = sB, Kr = sKr;
    u32 c = (lane < 16) ? h16[(size_t)img * 65536 + B * 16 + lane] : 0;
    u32 inc = c;
#pragma unroll
    for (int d = 1; d < 16; d <<= 1) {
      u32 o = __shfl_up(inc, (unsigned)d, 64);
      if (lane >= d) inc += o;
    }
    if (lane < 16) {
      u32 exc = inc - c;
      if (exc < Kr && inc >= Kr) { sThr = B * 16 + lane; sTake = Kr - exc; }
    }
  }
  __syncthreads();
  const u32 thr = sThr, take = sTake;
  if (sub == 0 && tid == 0) { thrG[img * 2] = thr; thrG[img * 2 + 1] = take; }

  // gather this block's slice
  const float* sc = scores + (size_t)img * NN;
  const int n0 = sub * 2048 + tid;
#pragma unroll
  for (int r = 0; r < 2; ++r) {
    int n = n0 + r * 1024;
    bool g = false;
    u32 k = 0;
    if (n < NN) {
      float s = sc[n];
      if (s > CONF_T) {
        k = desc_key(s);
        g = (k >> 16) <= thr;
      }
    }
    u64 bb = __ballot(g);
    if (bb) {
      int ldr = __ffsll((long long)bb) - 1;
      u32 base = 0;
      if (lane == ldr) base = atomicAdd(&candCnt[img], (u32)__popcll(bb));
      base = __shfl(base, ldr, 64);
      if (g) {
        u32 pos = base + (u32)__popcll(bb & ((1ull << lane) - 1ull));
        if (pos < CCAP) candKey[(size_t)img * CCAP + pos] = ((u64)k << 32) | (u32)n;
      }
    }
  }
}

// ------- Kernel 3: tie-resolve + class-group + NMS + output (16 blocks) -------
__global__ __launch_bounds__(1024) void k_finish(
    const int* __restrict__ clsArr, const float4* __restrict__ boxes,
    const u32* __restrict__ candCnt, const u64* __restrict__ candKey,
    const u32* __restrict__ thrG, float* __restrict__ out) {
  const int img = blockIdx.x, tid = threadIdx.x, lane = tid & 63;
  const size_t imgN = (size_t)img * NN;

  __shared__ u64 ck[CCAP];  // candidates; reused as svKey after compact
  __shared__ u64 pk[1024];
  __shared__ float lx1[1024], ly1[1024], lx2[1024], ly2[1024];
  __shared__ u8 clsV[1024];
  __shared__ u8 aliveF[1024];
  __shared__ u16 clsList[1024];
  __shared__ u16 clsSorted[1024];
  __shared__ u16 svP[1024];
  __shared__ u64 tl[256];
  __shared__ u32 clsCnt[NCLS];
  __shared__ u32 clsStart[NCLS + 1];
  __shared__ u32 wtc[2];
  __shared__ u32 sTie, sP, sSv;

  float* outImg = out + (size_t)img * MAXDET * 6;
  for (int t = tid; t < MAXDET * 6; t += 1024) outImg[t] = 0.0f;
  if (tid == 0) { sTie = 0; sP = 0; sSv = 0; }
  if (tid < NCLS) clsCnt[tid] = 0;
  const u32 cntRaw = candCnt[img];
  const u32 cnt = cntRaw < CCAP ? cntRaw : CCAP;
  const u32 thr = thrG[img * 2], take = thrG[img * 2 + 1];
  for (u32 t = tid; t < cnt; t += 1024) ck[t] = candKey[(size_t)img * CCAP + t];
  __syncthreads();

  // tie set at the threshold prefix
  for (u32 t = tid; t < cnt; t += 1024) {
    if ((u32)(ck[t] >> 48) == thr) {
      u32 s = atomicAdd(&sTie, 1u);
      if (s < 256) tl[s] = ck[t];
    }
  }
  __syncthreads();
  const u32 tieCnt = sTie;

  // mark dead ties + compact participants
  for (u32 t = tid; t < cnt; t += 1024) {
    u64 e = ck[t];
    bool keep = true;
    if (tieCnt > take && (u32)(e >> 48) == thr) {
      u32 tc = tieCnt < 256 ? tieCnt : 256;
      u32 r = 0;
      for (u32 o = 0; o < tc; ++o) r += (tl[o] < e) ? 1u : 0u;
      keep = (r < take);
    }
    if (keep) {
      u32 p = atomicAdd(&sP, 1u);
      if (p < 1024) pk[p] = e;
    }
  }
  __syncthreads();
  const int Pcnt = (int)(sP < 1024 ? sP : 1024);

  // fetch cls/box; class counts
  int myC = -1;
  u32 arb = 0;
  aliveF[tid] = (tid < Pcnt) ? 1 : 0;
  if (tid < Pcnt) {
    u64 e = pk[tid];
    u32 n = (u32)e;
    int c = clsArr[imgN + n];
    float4 bx = boxes[imgN + n];
    lx1[tid] = bx.x; ly1[tid] = bx.y; lx2[tid] = bx.z; ly2[tid] = bx.w;
    clsV[tid] = (u8)c;
    myC = c;
    arb = atomicAdd(&clsCnt[c], 1u);
  }
  __syncthreads();

  // class starts (2-wave scan over 80 counts)
  if (tid < 128) {
    u32 v = (tid < NCLS) ? clsCnt[tid] : 0;
    u32 inc = v;
#pragma unroll
    for (int d = 1; d < 64; d <<= 1) {
      u32 o = __shfl_up(inc, (unsigned)d, 64);
      if (lane >= d) inc += o;
    }
    if (lane == 63) wtc[tid >> 6] = inc;
  }
  __syncthreads();
  if (tid < 128) {
    u32 v = (tid < NCLS) ? clsCnt[tid] : 0;
    u32 inc = v;
#pragma unroll
    for (int d = 1; d < 64; d <<= 1) {
      u32 o = __shfl_up(inc, (unsigned)d, 64);
      if (lane >= d) inc += o;
    }
    u32 off = (tid >= 64) ? wtc[0] : 0;
    if (tid <= NCLS) clsStart[tid] = off + inc - v;
    if (tid == NCLS - 1) clsStart[NCLS] = off + inc;
  }
  __syncthreads();
  if (tid < Pcnt) clsList[clsStart[myC] + arb] = (u16)tid;
  __syncthreads();
  if (tid < Pcnt) {
    u32 s = clsStart[myC], e2 = clsStart[myC + 1];
    u64 myk = pk[tid];
    u32 r = 0;
    for (u32 q = s; q < e2; ++q) r += (pk[clsList[q]] < myk) ? 1u : 0u;
    clsSorted[s + r] = (u16)tid;
  }
  __syncthreads();

  // per-class sequential greedy NMS (one wave per class)
  {
    const int wid2 = tid >> 6;
    for (int c = wid2; c < NCLS; c += 16) {
      int s = (int)clsStart[c], e2 = (int)clsStart[c + 1];
      float offc = __fmul_rn((float)c, 4096.0f);
      for (int i = s; i < e2; ++i) {
        int ti = (int)clsSorted[i];
        if (!aliveF[ti]) continue;  // wave-uniform
        float ix1 = __fadd_rn(lx1[ti], offc), iy1 = __fadd_rn(ly1[ti], offc);
        float ix2 = __fadd_rn(lx2[ti], offc), iy2 = __fadd_rn(ly2[ti], offc);
        float ia = __fmul_rn(__fsub_rn(ix2, ix1), __fsub_rn(iy2, iy1));
        for (int jb = i + 1 + lane; jb < e2; jb += 64) {
          int tj = (int)clsSorted[jb];
          float jx1 = __fadd_rn(lx1[tj], offc), jy1 = __fadd_rn(ly1[tj], offc);
          float jx2 = __fadd_rn(lx2[tj], offc), jy2 = __fadd_rn(ly2[tj], offc);
          float ja = __fmul_rn(__fsub_rn(jx2, jx1), __fsub_rn(jy2, jy1));
          float xx1 = fmaxf(ix1, jx1), yy1 = fmaxf(iy1, jy1);
          float xx2 = fminf(ix2, jx2), yy2 = fminf(iy2, jy2);
          float ww = fmaxf(__fsub_rn(xx2, xx1), 0.0f);
          float hh = fmaxf(__fsub_rn(yy2, yy1), 0.0f);
          float inter = __fmul_rn(ww, hh);
          float den = __fadd_rn(__fsub_rn(__fadd_rn(ia, ja), inter), 1e-9f);
          if (inter > __fmul_rn(IOU_T, den)) aliveF[tj] = 0;
        }
      }
    }
  }
  __syncthreads();

  // survivor rank-by-count + output
  u64* svKey = ck;  // ck dead now
  if (tid < Pcnt && aliveF[tid]) {
    u32 s = atomicAdd(&sSv, 1u);
    svKey[s] = pk[tid];
    svP[s] = (u16)tid;
  }
  __syncthreads();
  const u32 S = sSv;
  for (u32 s = tid; s < S; s += 1024) {
    u64 myk = svKey[s];
    u32 r = 0;
    for (u32 o = 0; o < S; ++o) r += (svKey[o] < myk) ? 1u : 0u;
    if (r < MAXDET) {
      int p = (int)svP[s];
      float* o6 = outImg + (size_t)r * 6;
      o6[0] = lx1[p];
      o6[1] = ly1[p];
      o6[2] = lx2[p];
      o6[3] = ly2[p];
      o6[4] = inv_key((u32)(myk >> 32));
      o6[5] = (float)clsV[p];
    }
  }
}

extern "C" void kernel_launch(void* const* d_in, const int* in_sizes, int n_in,
                              void* d_out, int out_size, void* d_ws, size_t ws_size,
                              hipStream_t stream) {
  const float* pred = (const float*)d_in[0];
  char* ws = (char*)d_ws;
  size_t off = 0;
  float* scores = (float*)(ws + off); off += (size_t)NB * NN * 4;
  int* clsArr = (int*)(ws + off); off += (size_t)NB * NN * 4;
  float4* boxes = (float4*)(ws + off); off += (size_t)NB * NN * 16;
  u32* zbase = (u32*)(ws + off);
  u32* h12 = (u32*)(ws + off); off += (size_t)NB * 4096 * 4;
  u32* h16 = (u32*)(ws + off); off += (size_t)NB * 65536 * 4;
  u32* candCnt = (u32*)(ws + off); off += (size_t)NB * 4;
  u32* thrG = (u32*)(ws + off); off += (size_t)NB * 2 * 4;
  u64* candKey = (u64*)(ws + off); off += (size_t)NB * CCAP * 8;
  if (off > ws_size) return;

  const int TOTZ = NB * 4096 + NB * 65536 + NB + NB * 2;
  float* outp = (float*)d_out;
  k_zero<<<(TOTZ + 1023) / 1024, 1024, 0, stream>>>(zbase, TOTZ);
  dim3 gridD((NN + 255) / 256, NB);
  k_decode<<<gridD, 256, 0, stream>>>(pred, scores, clsArr, boxes, h12, h16);
  dim3 gridG(13, NB);
  k_gather<<<gridG, 1024, 0, stream>>>(scores, h12, h16, candCnt, candKey, thrG);
  k_finish<<<NB, 1024, 0, stream>>>(clsArr, boxes, candCnt, candKey, thrG, outp);
}

// Round 10
// 173.743 us; speedup vs baseline: 1.1331x; 1.1331x over previous
//
#include <hip/hip_runtime.h>
#include <stdint.h>

#define NB 16
#define NN 25200
#define NCLS 80
#define NROW 85
#define KPRE 1000
#define MAXDET 300
#define CONF_T 0.25f
#define IOU_T 0.45f
#define CCAP 4096  // candidate capacity per image
#define HCOPY 4    // rotated h12 copies (flush-contention relief)

typedef unsigned long long u64;
typedef unsigned int u32;
typedef unsigned short u16;
typedef unsigned char u8;

// Descending-order sortable key: higher score -> smaller key; ties by index.
__device__ __forceinline__ u32 desc_key(float s) {
  u32 u = __float_as_uint(s);
  u = (u & 0x80000000u) ? ~u : (u | 0x80000000u);
  return ~u;
}
__device__ __forceinline__ float inv_key(u32 k) {
  u32 u = ~k;
  u32 o = (u & 0x80000000u) ? (u & 0x7fffffffu) : ~u;
  return __uint_as_float(o);
}

// ---------------- Kernel 0: zero hist/counter region ----------------
__global__ __launch_bounds__(1024) void k_zero(u32* __restrict__ z, int total) {
  int i = blockIdx.x * 1024 + threadIdx.x;
  if (i < total) z[i] = 0;
}

// ------- Kernel 1: decode (LDS-staged coalesced) + fused 12-bit hist -------
__global__ __launch_bounds__(256) void k_decode(
    const float* __restrict__ pred, float* __restrict__ scores,
    int* __restrict__ clsArr, float4* __restrict__ boxes,
    u32* __restrict__ h12) {
  __shared__ __align__(16) float lds[4][1360];
  __shared__ u32 h[4096];
  const int tid = threadIdx.x;
  const int wid = tid >> 6, lane = tid & 63;
  const int q = lane & 3, rl = lane >> 2;
  const int img = blockIdx.y;
  for (int t = tid; t < 4096; t += 256) h[t] = 0;
  float* L = lds[wid];
  const float* base = pred + (size_t)img * NN * NROW;
  const int waveRow0 = blockIdx.x * 256 + wid * 64;
  const int IMGF = NN * NROW;
  __syncthreads();
  for (int c = 0; c < 4; ++c) {
    const int row0 = waveRow0 + c * 16;
    const int fbase = row0 * NROW;
#pragma unroll
    for (int k = 0; k < 5; ++k) {
      int off = k * 256 + lane * 4;
      int src = (fbase + off + 4 <= IMGF) ? (fbase + off) : 0;
      float4 v;
      __builtin_memcpy(&v, base + src, 16);
      *(float4*)(L + off) = v;
    }
    if (lane < 20) {
      int off = 1280 + lane * 4;
      int src = (fbase + off + 4 <= IMGF) ? (fbase + off) : 0;
      float4 v;
      __builtin_memcpy(&v, base + src, 16);
      *(float4*)(L + off) = v;
    }
    __syncthreads();
    const int row = row0 + rl;
    const bool rowOK = (row < NN);
    const float* R = L + rl * 85;
    float obj = R[4];
    float best = -1.0f;
    int bj = 0;
    const int j0 = q * 20;
#pragma unroll
    for (int jj = 0; jj < 20; ++jj) {
      float v = __fmul_rn(R[5 + j0 + jj], obj);
      if (v > best) { best = v; bj = j0 + jj; }
    }
#pragma unroll
    for (int d = 1; d < 4; d <<= 1) {
      float b2 = __shfl_xor(best, d, 64);
      int j2 = __shfl_xor(bj, d, 64);
      if (b2 > best || (b2 == best && j2 < bj)) { best = b2; bj = j2; }
    }
    bool valid = (best > CONF_T);
    if (q == 0 && rowOK) {
      if (valid) atomicAdd(&h[desc_key(best) >> 20], 1u);
      int gid = img * NN + row;
      float x = R[0], y = R[1], w = R[2], hgt = R[3];
      float hx = __fmul_rn(w, 0.5f), hy = __fmul_rn(hgt, 0.5f);
      float4 bx;
      bx.x = __fsub_rn(x, hx);
      bx.y = __fsub_rn(y, hy);
      bx.z = __fadd_rn(x, hx);
      bx.w = __fadd_rn(y, hy);
      scores[gid] = valid ? best : -1.0f;
      clsArr[gid] = bj;
      boxes[gid] = bx;
    }
    __syncthreads();
  }
  // flush into one of HCOPY rotated copies to cut atomic contention
  u32* hp = h12 + ((size_t)img * HCOPY + (blockIdx.x & (HCOPY - 1))) * 4096;
  for (int t = tid; t < 4096; t += 256) {
    u32 v = h[t];
    if (v) atomicAdd(&hp[t], v);
  }
}

// ------- Kernel 2: distributed gather (13 blocks/image), h12-only -------
__global__ __launch_bounds__(1024) void k_gather(
    const float* __restrict__ scores, const u32* __restrict__ h12,
    u32* __restrict__ candCnt, u64* __restrict__ candKey,
    u32* __restrict__ thrG) {
  const int img = blockIdx.y, sub = blockIdx.x;
  const int tid = threadIdx.x, lane = tid & 63;
  __shared__ u32 wt[16];
  __shared__ u32 sB, sKr;
  if (tid == 0) sB = 0xFFFFFFFFu;

  // sum the HCOPY histogram copies, scan to find 12-bit bucket B of key #1000
  const u32* hb = h12 + (size_t)img * HCOPY * 4096;
  uint4 hv = make_uint4(0, 0, 0, 0);
#pragma unroll
  for (int c = 0; c < HCOPY; ++c) {
    uint4 v = *(const uint4*)(hb + c * 4096 + tid * 4);
    hv.x += v.x; hv.y += v.y; hv.z += v.z; hv.w += v.w;
  }
  u32 s4 = hv.x + hv.y + hv.z + hv.w;
  u32 incl = s4;
#pragma unroll
  for (int d = 1; d < 64; d <<= 1) {
    u32 o = __shfl_up(incl, (unsigned)d, 64);
    if (lane >= d) incl += o;
  }
  if (lane == 63) wt[tid >> 6] = incl;
  __syncthreads();
  {
    u32 woff = 0;
    int w = tid >> 6;
    for (int x = 0; x < w; ++x) woff += wt[x];
    u32 P = woff + incl - s4;
    if (P < KPRE && P + s4 >= KPRE) {
      u32 cacc = P, b = 3;
      if (cacc + hv.x >= KPRE) b = 0;
      else {
        cacc += hv.x;
        if (cacc + hv.y >= KPRE) b = 1;
        else {
          cacc += hv.y;
          if (cacc + hv.z >= KPRE) b = 2;
          else cacc += hv.z;
        }
      }
      sB = tid * 4 + b;
      sKr = KPRE - cacc;
    }
  }
  __syncthreads();
  const u32 B = sB;
  const u32 thr12 = (B == 0xFFFFFFFFu) ? 0xFFFu : B;
  if (sub == 0 && tid == 0) {
    thrG[img * 2] = B;
    thrG[img * 2 + 1] = (B == 0xFFFFFFFFu) ? 0x7FFFFFFFu : sKr;
  }

  // gather this block's 2048-score slice
  const float* sc = scores + (size_t)img * NN;
  const int n0 = sub * 2048 + tid;
#pragma unroll
  for (int r = 0; r < 2; ++r) {
    int n = n0 + r * 1024;
    bool g = false;
    u32 k = 0;
    if (n < NN) {
      float s = sc[n];
      if (s > CONF_T) {
        k = desc_key(s);
        g = (k >> 20) <= thr12;
      }
    }
    u64 bb = __ballot(g);
    if (bb) {
      int ldr = __ffsll((long long)bb) - 1;
      u32 base = 0;
      if (lane == ldr) base = atomicAdd(&candCnt[img], (u32)__popcll(bb));
      base = __shfl(base, ldr, 64);
      if (g) {
        u32 pos = base + (u32)__popcll(bb & ((1ull << lane) - 1ull));
        if (pos < CCAP) candKey[(size_t)img * CCAP + pos] = ((u64)k << 32) | (u32)n;
      }
    }
  }
}

// ------- Kernel 3: refine + tie + class-group + NMS + output (16 blocks) -------
__global__ __launch_bounds__(1024) void k_finish(
    const int* __restrict__ clsArr, const float4* __restrict__ boxes,
    const u32* __restrict__ candCnt, const u64* __restrict__ candKey,
    const u32* __restrict__ thrG, float* __restrict__ out) {
  const int img = blockIdx.x, tid = threadIdx.x, lane = tid & 63;
  const size_t imgN = (size_t)img * NN;

  __shared__ u64 ck[CCAP];  // candidates; reused as svKey after compact
  __shared__ u64 pk[1024];
  __shared__ float lx1[1024], ly1[1024], lx2[1024], ly2[1024];
  __shared__ u8 clsV[1024];
  __shared__ u8 aliveF[1024];
  __shared__ u16 clsList[1024];
  __shared__ u16 clsSorted[1024];
  __shared__ u16 svP[1024];
  __shared__ u64 tl[256];
  __shared__ u32 subhist[256];
  __shared__ u32 clsCnt[NCLS];
  __shared__ u32 clsStart[NCLS + 1];
  __shared__ u32 wtc[4];
  __shared__ u32 sThr, sTake, sTie, sP, sSv;

  float* outImg = out + (size_t)img * MAXDET * 6;
  for (int t = tid; t < MAXDET * 6; t += 1024) outImg[t] = 0.0f;
  if (tid == 0) { sTie = 0; sP = 0; sSv = 0; sThr = 0xFFFFFFFFu; sTake = 0x7FFFFFFFu; }
  if (tid < NCLS) clsCnt[tid] = 0;
  if (tid < 256) subhist[tid] = 0;
  const u32 cntRaw = candCnt[img];
  const u32 cnt = cntRaw < CCAP ? cntRaw : CCAP;
  const u32 B = thrG[img * 2];
  const u32 Kr = thrG[img * 2 + 1];
  const bool noRef = (B == 0xFFFFFFFFu);
  for (u32 t = tid; t < cnt; t += 1024) ck[t] = candKey[(size_t)img * CCAP + t];
  __syncthreads();

  // ---- refinement: 8-bit sub-histogram (bits 19..12) over bucket-B cands ----
  if (!noRef) {
    for (u32 t = tid; t < cnt; t += 1024) {
      u32 key = (u32)(ck[t] >> 32);
      if ((key >> 20) == B) atomicAdd(&subhist[(key >> 12) & 255], 1u);
    }
  }
  __syncthreads();
  {
    u32 myc = (tid < 256) ? subhist[tid] : 0;
    u32 inc2 = myc;
#pragma unroll
    for (int d = 1; d < 64; d <<= 1) {
      u32 o = __shfl_up(inc2, (unsigned)d, 64);
      if (lane >= d) inc2 += o;
    }
    if (tid < 256 && lane == 63) wtc[tid >> 6] = inc2;
    __syncthreads();
    if (!noRef && tid < 256) {
      u32 off = 0;
      int w = tid >> 6;
      for (int x = 0; x < w; ++x) off += wtc[x];
      u32 inc = off + inc2, exc = inc - myc;
      if (exc < Kr && inc >= Kr) {
        sThr = (B << 8) | (u32)tid;  // exact 20-bit threshold
        sTake = Kr - exc;
      }
    }
  }
  __syncthreads();
  const u32 thr20 = sThr, take = sTake;

  // ---- tie set at the 20-bit threshold ----
  if (!noRef) {
    for (u32 t = tid; t < cnt; t += 1024) {
      u64 e = ck[t];
      if ((u32)(e >> 44) == thr20) {
        u32 s = atomicAdd(&sTie, 1u);
        if (s < 256) tl[s] = e;
      }
    }
  }
  __syncthreads();
  const u32 tieCnt = sTie;

  // ---- keep predicate + compact participants (exactly KPRE normally) ----
  for (u32 t = tid; t < cnt; t += 1024) {
    u64 e = ck[t];
    bool keep;
    if (noRef) {
      keep = true;
    } else {
      u32 p20 = (u32)(e >> 44);
      if (p20 < thr20) keep = true;
      else if (p20 > thr20) keep = false;
      else if (tieCnt <= take) keep = true;
      else {
        u32 tc = tieCnt < 256 ? tieCnt : 256;
        u32 r = 0;
        for (u32 o = 0; o < tc; ++o) r += (tl[o] < e) ? 1u : 0u;
        keep = (r < take);
      }
    }
    if (keep) {
      u32 p = atomicAdd(&sP, 1u);
      if (p < 1024) pk[p] = e;
    }
  }
  __syncthreads();
  const int Pcnt = (int)(sP < 1024 ? sP : 1024);

  // ---- fetch cls/box; class counts ----
  int myC = -1;
  u32 arb = 0;
  aliveF[tid] = (tid < Pcnt) ? 1 : 0;
  if (tid < Pcnt) {
    u64 e = pk[tid];
    u32 n = (u32)e;
    int c = clsArr[imgN + n];
    float4 bx = boxes[imgN + n];
    lx1[tid] = bx.x; ly1[tid] = bx.y; lx2[tid] = bx.z; ly2[tid] = bx.w;
    clsV[tid] = (u8)c;
    myC = c;
    arb = atomicAdd(&clsCnt[c], 1u);
  }
  __syncthreads();

  // ---- class starts (2-wave scan over 80 counts) ----
  if (tid < 128) {
    u32 v = (tid < NCLS) ? clsCnt[tid] : 0;
    u32 inc = v;
#pragma unroll
    for (int d = 1; d < 64; d <<= 1) {
      u32 o = __shfl_up(inc, (unsigned)d, 64);
      if (lane >= d) inc += o;
    }
    if (lane == 63) wtc[tid >> 6] = inc;
  }
  __syncthreads();
  if (tid < 128) {
    u32 v = (tid < NCLS) ? clsCnt[tid] : 0;
    u32 inc = v;
#pragma unroll
    for (int d = 1; d < 64; d <<= 1) {
      u32 o = __shfl_up(inc, (unsigned)d, 64);
      if (lane >= d) inc += o;
    }
    u32 off = (tid >= 64) ? wtc[0] : 0;
    if (tid <= NCLS) clsStart[tid] = off + inc - v;
    if (tid == NCLS - 1) clsStart[NCLS] = off + inc;
  }
  __syncthreads();
  if (tid < Pcnt) clsList[clsStart[myC] + arb] = (u16)tid;
  __syncthreads();
  if (tid < Pcnt) {
    u32 s = clsStart[myC], e2 = clsStart[myC + 1];
    u64 myk = pk[tid];
    u32 r = 0;
    for (u32 q = s; q < e2; ++q) r += (pk[clsList[q]] < myk) ? 1u : 0u;
    clsSorted[s + r] = (u16)tid;
  }
  __syncthreads();

  // ---- per-class sequential greedy NMS (one wave per class) ----
  {
    const int wid2 = tid >> 6;
    for (int c = wid2; c < NCLS; c += 16) {
      int s = (int)clsStart[c], e2 = (int)clsStart[c + 1];
      float offc = __fmul_rn((float)c, 4096.0f);
      for (int i = s; i < e2; ++i) {
        int ti = (int)clsSorted[i];
        if (!aliveF[ti]) continue;  // wave-uniform
        float ix1 = __fadd_rn(lx1[ti], offc), iy1 = __fadd_rn(ly1[ti], offc);
        float ix2 = __fadd_rn(lx2[ti], offc), iy2 = __fadd_rn(ly2[ti], offc);
        float ia = __fmul_rn(__fsub_rn(ix2, ix1), __fsub_rn(iy2, iy1));
        for (int jb = i + 1 + lane; jb < e2; jb += 64) {
          int tj = (int)clsSorted[jb];
          float jx1 = __fadd_rn(lx1[tj], offc), jy1 = __fadd_rn(ly1[tj], offc);
          float jx2 = __fadd_rn(lx2[tj], offc), jy2 = __fadd_rn(ly2[tj], offc);
          float ja = __fmul_rn(__fsub_rn(jx2, jx1), __fsub_rn(jy2, jy1));
          float xx1 = fmaxf(ix1, jx1), yy1 = fmaxf(iy1, jy1);
          float xx2 = fminf(ix2, jx2), yy2 = fminf(iy2, jy2);
          float ww = fmaxf(__fsub_rn(xx2, xx1), 0.0f);
          float hh = fmaxf(__fsub_rn(yy2, yy1), 0.0f);
          float inter = __fmul_rn(ww, hh);
          float den = __fadd_rn(__fsub_rn(__fadd_rn(ia, ja), inter), 1e-9f);
          if (inter > __fmul_rn(IOU_T, den)) aliveF[tj] = 0;
        }
      }
    }
  }
  __syncthreads();

  // ---- survivor rank-by-count + output ----
  u64* svKey = ck;  // ck dead now
  if (tid < Pcnt && aliveF[tid]) {
    u32 s = atomicAdd(&sSv, 1u);
    svKey[s] = pk[tid];
    svP[s] = (u16)tid;
  }
  __syncthreads();
  const u32 S = sSv;
  for (u32 s = tid; s < S; s += 1024) {
    u64 myk = svKey[s];
    u32 r = 0;
    for (u32 o = 0; o < S; ++o) r += (svKey[o] < myk) ? 1u : 0u;
    if (r < MAXDET) {
      int p = (int)svP[s];
      float* o6 = outImg + (size_t)r * 6;
      o6[0] = lx1[p];
      o6[1] = ly1[p];
      o6[2] = lx2[p];
      o6[3] = ly2[p];
      o6[4] = inv_key((u32)(myk >> 32));
      o6[5] = (float)clsV[p];
    }
  }
}

extern "C" void kernel_launch(void* const* d_in, const int* in_sizes, int n_in,
                              void* d_out, int out_size, void* d_ws, size_t ws_size,
                              hipStream_t stream) {
  const float* pred = (const float*)d_in[0];
  char* ws = (char*)d_ws;
  size_t off = 0;
  float* scores = (float*)(ws + off); off += (size_t)NB * NN * 4;
  int* clsArr = (int*)(ws + off); off += (size_t)NB * NN * 4;
  float4* boxes = (float4*)(ws + off); off += (size_t)NB * NN * 16;
  u32* zbase = (u32*)(ws + off);
  u32* h12 = (u32*)(ws + off); off += (size_t)NB * HCOPY * 4096 * 4;
  u32* candCnt = (u32*)(ws + off); off += (size_t)NB * 4;
  u32* thrG = (u32*)(ws + off); off += (size_t)NB * 2 * 4;
  u64* candKey = (u64*)(ws + off); off += (size_t)NB * CCAP * 8;
  if (off > ws_size) return;

  const int TOTZ = NB * HCOPY * 4096 + NB + NB * 2;
  float* outp = (float*)d_out;
  k_zero<<<(TOTZ + 1023) / 1024, 1024, 0, stream>>>(zbase, TOTZ);
  dim3 gridD((NN + 255) / 256, NB);
  k_decode<<<gridD, 256, 0, stream>>>(pred, scores, clsArr, boxes, h12);
  dim3 gridG(13, NB);
  k_gather<<<gridG, 1024, 0, stream>>>(scores, h12, candCnt, candKey, thrG);
  k_finish<<<NB, 1024, 0, stream>>>(clsArr, boxes, candCnt, candKey, thrG, outp);
}

// Round 11
// 110.122 us; speedup vs baseline: 1.7877x; 1.5777x over previous
//
#include <hip/hip_runtime.h>
#include <stdint.h>

#define NB 16
#define NN 25200
#define NCLS 80
#define NROW 85
#define KPRE 1000
#define MAXDET 300
#define CONF_T 0.25f
#define IOU_T 0.45f
#define NSLICE 13
#define SLICECAP 2048
#define CCAP 4096  // total candidate capacity per image (LDS)
#define HCOPY 4    // rotated h12 copies (flush-contention relief)

typedef unsigned long long u64;
typedef unsigned int u32;
typedef unsigned short u16;
typedef unsigned char u8;

// Descending-order sortable key: higher score -> smaller key; ties by index.
__device__ __forceinline__ u32 desc_key(float s) {
  u32 u = __float_as_uint(s);
  u = (u & 0x80000000u) ? ~u : (u | 0x80000000u);
  return ~u;
}
__device__ __forceinline__ float inv_key(u32 k) {
  u32 u = ~k;
  u32 o = (u & 0x80000000u) ? (u & 0x7fffffffu) : ~u;
  return __uint_as_float(o);
}

// ---------------- Kernel 0: zero h12 region ----------------
__global__ __launch_bounds__(1024) void k_zero(u32* __restrict__ z, int total) {
  int i = blockIdx.x * 1024 + threadIdx.x;
  if (i < total) z[i] = 0;
}

// ------- Kernel 1: decode (LDS-staged coalesced) + fused 12-bit hist -------
__global__ __launch_bounds__(256) void k_decode(
    const float* __restrict__ pred, float* __restrict__ scores,
    int* __restrict__ clsArr, float4* __restrict__ boxes,
    u32* __restrict__ h12) {
  __shared__ __align__(16) float lds[4][1360];
  __shared__ u32 h[4096];
  const int tid = threadIdx.x;
  const int wid = tid >> 6, lane = tid & 63;
  const int q = lane & 3, rl = lane >> 2;
  const int img = blockIdx.y;
  for (int t = tid; t < 4096; t += 256) h[t] = 0;
  float* L = lds[wid];
  const float* base = pred + (size_t)img * NN * NROW;
  const int waveRow0 = blockIdx.x * 256 + wid * 64;
  const int IMGF = NN * NROW;
  __syncthreads();
  for (int c = 0; c < 4; ++c) {
    const int row0 = waveRow0 + c * 16;
    const int fbase = row0 * NROW;
#pragma unroll
    for (int k = 0; k < 5; ++k) {
      int off = k * 256 + lane * 4;
      int src = (fbase + off + 4 <= IMGF) ? (fbase + off) : 0;
      float4 v;
      __builtin_memcpy(&v, base + src, 16);
      *(float4*)(L + off) = v;
    }
    if (lane < 20) {
      int off = 1280 + lane * 4;
      int src = (fbase + off + 4 <= IMGF) ? (fbase + off) : 0;
      float4 v;
      __builtin_memcpy(&v, base + src, 16);
      *(float4*)(L + off) = v;
    }
    __syncthreads();
    const int row = row0 + rl;
    const bool rowOK = (row < NN);
    const float* R = L + rl * 85;
    float obj = R[4];
    float best = -1.0f;
    int bj = 0;
    const int j0 = q * 20;
#pragma unroll
    for (int jj = 0; jj < 20; ++jj) {
      float v = __fmul_rn(R[5 + j0 + jj], obj);
      if (v > best) { best = v; bj = j0 + jj; }
    }
#pragma unroll
    for (int d = 1; d < 4; d <<= 1) {
      float b2 = __shfl_xor(best, d, 64);
      int j2 = __shfl_xor(bj, d, 64);
      if (b2 > best || (b2 == best && j2 < bj)) { best = b2; bj = j2; }
    }
    bool valid = (best > CONF_T);
    if (q == 0 && rowOK) {
      if (valid) atomicAdd(&h[desc_key(best) >> 20], 1u);
      int gid = img * NN + row;
      float x = R[0], y = R[1], w = R[2], hgt = R[3];
      float hx = __fmul_rn(w, 0.5f), hy = __fmul_rn(hgt, 0.5f);
      float4 bx;
      bx.x = __fsub_rn(x, hx);
      bx.y = __fsub_rn(y, hy);
      bx.z = __fadd_rn(x, hx);
      bx.w = __fadd_rn(y, hy);
      scores[gid] = valid ? best : -1.0f;
      clsArr[gid] = bj;
      boxes[gid] = bx;
    }
    __syncthreads();
  }
  // flush into one of HCOPY rotated copies to cut atomic contention
  u32* hp = h12 + ((size_t)img * HCOPY + (blockIdx.x & (HCOPY - 1))) * 4096;
  for (int t = tid; t < 4096; t += 256) {
    u32 v = h[t];
    if (v) atomicAdd(&hp[t], v);
  }
}

// ------- Kernel 2: distributed gather, slice-local (NO global atomics) -------
__global__ __launch_bounds__(1024) void k_gather(
    const float* __restrict__ scores, const u32* __restrict__ h12,
    u32* __restrict__ candCntS, u64* __restrict__ candKey,
    u32* __restrict__ thrG) {
  const int img = blockIdx.y, sub = blockIdx.x;
  const int tid = threadIdx.x, lane = tid & 63;
  __shared__ u32 wt[16];
  __shared__ u32 sB, sKr, sPos;
  if (tid == 0) { sB = 0xFFFFFFFFu; sPos = 0; }

  // sum the HCOPY histogram copies, scan to find 12-bit bucket B of key #1000
  const u32* hb = h12 + (size_t)img * HCOPY * 4096;
  uint4 hv = make_uint4(0, 0, 0, 0);
#pragma unroll
  for (int c = 0; c < HCOPY; ++c) {
    uint4 v = *(const uint4*)(hb + c * 4096 + tid * 4);
    hv.x += v.x; hv.y += v.y; hv.z += v.z; hv.w += v.w;
  }
  u32 s4 = hv.x + hv.y + hv.z + hv.w;
  u32 incl = s4;
#pragma unroll
  for (int d = 1; d < 64; d <<= 1) {
    u32 o = __shfl_up(incl, (unsigned)d, 64);
    if (lane >= d) incl += o;
  }
  if (lane == 63) wt[tid >> 6] = incl;
  __syncthreads();
  {
    u32 woff = 0;
    int w = tid >> 6;
    for (int x = 0; x < w; ++x) woff += wt[x];
    u32 P = woff + incl - s4;
    if (P < KPRE && P + s4 >= KPRE) {
      u32 cacc = P, b = 3;
      if (cacc + hv.x >= KPRE) b = 0;
      else {
        cacc += hv.x;
        if (cacc + hv.y >= KPRE) b = 1;
        else {
          cacc += hv.y;
          if (cacc + hv.z >= KPRE) b = 2;
          else cacc += hv.z;
        }
      }
      sB = tid * 4 + b;
      sKr = KPRE - cacc;
    }
  }
  __syncthreads();
  const u32 B = sB;
  const u32 thr12 = (B == 0xFFFFFFFFu) ? 0xFFFu : B;
  if (sub == 0 && tid == 0) {
    thrG[img * 2] = B;
    thrG[img * 2 + 1] = (B == 0xFFFFFFFFu) ? 0x7FFFFFFFu : sKr;
  }

  // gather this block's 2048-score slice into its PRIVATE slice region
  u64* slice = candKey + ((size_t)img * NSLICE + sub) * SLICECAP;
  const float* sc = scores + (size_t)img * NN;
  const int n0 = sub * 2048 + tid;
#pragma unroll
  for (int r = 0; r < 2; ++r) {
    int n = n0 + r * 1024;
    bool g = false;
    u32 k = 0;
    if (n < NN) {
      float s = sc[n];
      if (s > CONF_T) {
        k = desc_key(s);
        g = (k >> 20) <= thr12;
      }
    }
    u64 bb = __ballot(g);
    if (bb) {
      int ldr = __ffsll((long long)bb) - 1;
      u32 base = 0;
      if (lane == ldr) base = atomicAdd(&sPos, (u32)__popcll(bb));  // LDS atomic
      base = __shfl(base, ldr, 64);
      if (g) {
        u32 pos = base + (u32)__popcll(bb & ((1ull << lane) - 1ull));
        slice[pos] = ((u64)k << 32) | (u32)n;  // pos < 2048 by construction
      }
    }
  }
  __syncthreads();
  if (tid == 0) candCntS[img * NSLICE + sub] = sPos;  // plain store
}

// ------- Kernel 3: concat + refine + tie + class-group + NMS + output -------
__global__ __launch_bounds__(1024) void k_finish(
    const int* __restrict__ clsArr, const float4* __restrict__ boxes,
    const u32* __restrict__ candCntS, const u64* __restrict__ candKey,
    const u32* __restrict__ thrG, float* __restrict__ out) {
  const int img = blockIdx.x, tid = threadIdx.x, lane = tid & 63;
  const size_t imgN = (size_t)img * NN;

  __shared__ u64 ck[CCAP];  // candidates; reused as svKey after compact
  __shared__ u64 pk[1024];
  __shared__ float lx1[1024], ly1[1024], lx2[1024], ly2[1024];
  __shared__ u8 clsV[1024];
  __shared__ u8 aliveF[1024];
  __shared__ u16 clsList[1024];
  __shared__ u16 clsSorted[1024];
  __shared__ u16 svP[1024];
  __shared__ u64 tl[256];
  __shared__ u32 subhist[256];
  __shared__ u32 clsCnt[NCLS];
  __shared__ u32 clsStart[NCLS + 1];
  __shared__ u32 sliceOff[NSLICE + 1];
  __shared__ u32 wtc[4];
  __shared__ u32 sThr, sTake, sTie, sP, sSv;

  float* outImg = out + (size_t)img * MAXDET * 6;
  for (int t = tid; t < MAXDET * 6; t += 1024) outImg[t] = 0.0f;
  if (tid == 0) {
    sTie = 0; sP = 0; sSv = 0; sThr = 0xFFFFFFFFu; sTake = 0x7FFFFFFFu;
    u32 acc = 0;
    for (int s = 0; s < NSLICE; ++s) {
      sliceOff[s] = acc;
      acc += candCntS[img * NSLICE + s];
    }
    sliceOff[NSLICE] = acc;
  }
  if (tid < NCLS) clsCnt[tid] = 0;
  if (tid < 256) subhist[tid] = 0;
  const u32 B = thrG[img * 2];
  const u32 Kr = thrG[img * 2 + 1];
  const bool noRef = (B == 0xFFFFFFFFu);
  __syncthreads();
  const u32 cnt = sliceOff[NSLICE] < CCAP ? sliceOff[NSLICE] : CCAP;
  // concat slices into LDS (order-independent downstream)
  for (int s = 0; s < NSLICE; ++s) {
    u32 o0 = sliceOff[s], c = sliceOff[s + 1] - o0;
    const u64* slice = candKey + ((size_t)img * NSLICE + s) * SLICECAP;
    for (u32 t = tid; t < c; t += 1024) {
      u32 d = o0 + t;
      if (d < CCAP) ck[d] = slice[t];
    }
  }
  __syncthreads();

  // ---- refinement: 8-bit sub-histogram (bits 19..12) over bucket-B cands ----
  if (!noRef) {
    for (u32 t = tid; t < cnt; t += 1024) {
      u32 key = (u32)(ck[t] >> 32);
      if ((key >> 20) == B) atomicAdd(&subhist[(key >> 12) & 255], 1u);
    }
  }
  __syncthreads();
  {
    u32 myc = (tid < 256) ? subhist[tid] : 0;
    u32 inc2 = myc;
#pragma unroll
    for (int d = 1; d < 64; d <<= 1) {
      u32 o = __shfl_up(inc2, (unsigned)d, 64);
      if (lane >= d) inc2 += o;
    }
    if (tid < 256 && lane == 63) wtc[tid >> 6] = inc2;
    __syncthreads();
    if (!noRef && tid < 256) {
      u32 off = 0;
      int w = tid >> 6;
      for (int x = 0; x < w; ++x) off += wtc[x];
      u32 inc = off + inc2, exc = inc - myc;
      if (exc < Kr && inc >= Kr) {
        sThr = (B << 8) | (u32)tid;  // exact 20-bit threshold
        sTake = Kr - exc;
      }
    }
  }
  __syncthreads();
  const u32 thr20 = sThr, take = sTake;

  // ---- tie set at the 20-bit threshold ----
  if (!noRef) {
    for (u32 t = tid; t < cnt; t += 1024) {
      u64 e = ck[t];
      if ((u32)(e >> 44) == thr20) {
        u32 s = atomicAdd(&sTie, 1u);
        if (s < 256) tl[s] = e;
      }
    }
  }
  __syncthreads();
  const u32 tieCnt = sTie;

  // ---- keep predicate + compact participants (exactly KPRE normally) ----
  for (u32 t = tid; t < cnt; t += 1024) {
    u64 e = ck[t];
    bool keep;
    if (noRef) {
      keep = true;
    } else {
      u32 p20 = (u32)(e >> 44);
      if (p20 < thr20) keep = true;
      else if (p20 > thr20) keep = false;
      else if (tieCnt <= take) keep = true;
      else {
        u32 tc = tieCnt < 256 ? tieCnt : 256;
        u32 r = 0;
        for (u32 o = 0; o < tc; ++o) r += (tl[o] < e) ? 1u : 0u;
        keep = (r < take);
      }
    }
    if (keep) {
      u32 p = atomicAdd(&sP, 1u);
      if (p < 1024) pk[p] = e;
    }
  }
  __syncthreads();
  const int Pcnt = (int)(sP < 1024 ? sP : 1024);

  // ---- fetch cls/box; class counts ----
  int myC = -1;
  u32 arb = 0;
  aliveF[tid] = (tid < Pcnt) ? 1 : 0;
  if (tid < Pcnt) {
    u64 e = pk[tid];
    u32 n = (u32)e;
    int c = clsArr[imgN + n];
    float4 bx = boxes[imgN + n];
    lx1[tid] = bx.x; ly1[tid] = bx.y; lx2[tid] = bx.z; ly2[tid] = bx.w;
    clsV[tid] = (u8)c;
    myC = c;
    arb = atomicAdd(&clsCnt[c], 1u);
  }
  __syncthreads();

  // ---- class starts (2-wave scan over 80 counts) ----
  if (tid < 128) {
    u32 v = (tid < NCLS) ? clsCnt[tid] : 0;
    u32 inc = v;
#pragma unroll
    for (int d = 1; d < 64; d <<= 1) {
      u32 o = __shfl_up(inc, (unsigned)d, 64);
      if (lane >= d) inc += o;
    }
    if (lane == 63) wtc[tid >> 6] = inc;
  }
  __syncthreads();
  if (tid < 128) {
    u32 v = (tid < NCLS) ? clsCnt[tid] : 0;
    u32 inc = v;
#pragma unroll
    for (int d = 1; d < 64; d <<= 1) {
      u32 o = __shfl_up(inc, (unsigned)d, 64);
      if (lane >= d) inc += o;
    }
    u32 off = (tid >= 64) ? wtc[0] : 0;
    if (tid <= NCLS) clsStart[tid] = off + inc - v;
    if (tid == NCLS - 1) clsStart[NCLS] = off + inc;
  }
  __syncthreads();
  if (tid < Pcnt) clsList[clsStart[myC] + arb] = (u16)tid;
  __syncthreads();
  if (tid < Pcnt) {
    u32 s = clsStart[myC], e2 = clsStart[myC + 1];
    u64 myk = pk[tid];
    u32 r = 0;
    for (u32 q = s; q < e2; ++q) r += (pk[clsList[q]] < myk) ? 1u : 0u;
    clsSorted[s + r] = (u16)tid;
  }
  __syncthreads();

  // ---- per-class sequential greedy NMS (one wave per class) ----
  {
    const int wid2 = tid >> 6;
    for (int c = wid2; c < NCLS; c += 16) {
      int s = (int)clsStart[c], e2 = (int)clsStart[c + 1];
      float offc = __fmul_rn((float)c, 4096.0f);
      for (int i = s; i < e2; ++i) {
        int ti = (int)clsSorted[i];
        if (!aliveF[ti]) continue;  // wave-uniform
        float ix1 = __fadd_rn(lx1[ti], offc), iy1 = __fadd_rn(ly1[ti], offc);
        float ix2 = __fadd_rn(lx2[ti], offc), iy2 = __fadd_rn(ly2[ti], offc);
        float ia = __fmul_rn(__fsub_rn(ix2, ix1), __fsub_rn(iy2, iy1));
        for (int jb = i + 1 + lane; jb < e2; jb += 64) {
          int tj = (int)clsSorted[jb];
          float jx1 = __fadd_rn(lx1[tj], offc), jy1 = __fadd_rn(ly1[tj], offc);
          float jx2 = __fadd_rn(lx2[tj], offc), jy2 = __fadd_rn(ly2[tj], offc);
          float ja = __fmul_rn(__fsub_rn(jx2, jx1), __fsub_rn(jy2, jy1));
          float xx1 = fmaxf(ix1, jx1), yy1 = fmaxf(iy1, jy1);
          float xx2 = fminf(ix2, jx2), yy2 = fminf(iy2, jy2);
          float ww = fmaxf(__fsub_rn(xx2, xx1), 0.0f);
          float hh = fmaxf(__fsub_rn(yy2, yy1), 0.0f);
          float inter = __fmul_rn(ww, hh);
          float den = __fadd_rn(__fsub_rn(__fadd_rn(ia, ja), inter), 1e-9f);
          if (inter > __fmul_rn(IOU_T, den)) aliveF[tj] = 0;
        }
      }
    }
  }
  __syncthreads();

  // ---- survivor rank-by-count + output ----
  u64* svKey = ck;  // ck dead now
  if (tid < Pcnt && aliveF[tid]) {
    u32 s = atomicAdd(&sSv, 1u);
    svKey[s] = pk[tid];
    svP[s] = (u16)tid;
  }
  __syncthreads();
  const u32 S = sSv;
  for (u32 s = tid; s < S; s += 1024) {
    u64 myk = svKey[s];
    u32 r = 0;
    for (u32 o = 0; o < S; ++o) r += (svKey[o] < myk) ? 1u : 0u;
    if (r < MAXDET) {
      int p = (int)svP[s];
      float* o6 = outImg + (size_t)r * 6;
      o6[0] = lx1[p];
      o6[1] = ly1[p];
      o6[2] = lx2[p];
      o6[3] = ly2[p];
      o6[4] = inv_key((u32)(myk >> 32));
      o6[5] = (float)clsV[p];
    }
  }
}

extern "C" void kernel_launch(void* const* d_in, const int* in_sizes, int n_in,
                              void* d_out, int out_size, void* d_ws, size_t ws_size,
                              hipStream_t stream) {
  const float* pred = (const float*)d_in[0];
  char* ws = (char*)d_ws;
  size_t off = 0;
  float* scores = (float*)(ws + off); off += (size_t)NB * NN * 4;
  int* clsArr = (int*)(ws + off); off += (size_t)NB * NN * 4;
  float4* boxes = (float4*)(ws + off); off += (size_t)NB * NN * 16;
  u32* h12 = (u32*)(ws + off); off += (size_t)NB * HCOPY * 4096 * 4;
  u32* candCntS = (u32*)(ws + off); off += (size_t)NB * NSLICE * 4;
  u32* thrG = (u32*)(ws + off); off += (size_t)NB * 2 * 4;
  u64* candKey = (u64*)(ws + off); off += (size_t)NB * NSLICE * SLICECAP * 8;
  if (off > ws_size) return;

  const int TOTZ = NB * HCOPY * 4096;
  float* outp = (float*)d_out;
  k_zero<<<(TOTZ + 1023) / 1024, 1024, 0, stream>>>(h12, TOTZ);
  dim3 gridD((NN + 255) / 256, NB);
  k_decode<<<gridD, 256, 0, stream>>>(pred, scores, clsArr, boxes, h12);
  dim3 gridG(NSLICE, NB);
  k_gather<<<gridG, 1024, 0, stream>>>(scores, h12, candCntS, candKey, thrG);
  k_finish<<<NB, 1024, 0, stream>>>(clsArr, boxes, candCntS, candKey, thrG, outp);
}

// Round 12
// 109.387 us; speedup vs baseline: 1.7997x; 1.0067x over previous
//
#include <hip/hip_runtime.h>
#include <stdint.h>

#define NB 16
#define NN 25200
#define NCLS 80
#define NROW 85
#define KPRE 1000
#define MAXDET 300
#define CONF_T 0.25f
#define IOU_T 0.45f
#define CCAP 4096  // candidate capacity (LDS)
#define HCOPY 4    // rotated h12 copies (flush-contention relief)

typedef unsigned long long u64;
typedef unsigned int u32;
typedef unsigned short u16;
typedef unsigned char u8;

// Descending-order sortable key: higher score -> smaller key; ties by index.
__device__ __forceinline__ u32 desc_key(float s) {
  u32 u = __float_as_uint(s);
  u = (u & 0x80000000u) ? ~u : (u | 0x80000000u);
  return ~u;
}
__device__ __forceinline__ float inv_key(u32 k) {
  u32 u = ~k;
  u32 o = (u & 0x80000000u) ? (u & 0x7fffffffu) : ~u;
  return __uint_as_float(o);
}

// ---------------- Kernel 0: zero h12 region ----------------
__global__ __launch_bounds__(1024) void k_zero(u32* __restrict__ z, int total) {
  int i = blockIdx.x * 1024 + threadIdx.x;
  if (i < total) z[i] = 0;
}

// ------- Kernel 1: decode (LDS-staged coalesced) + fused 12-bit hist -------
__global__ __launch_bounds__(256) void k_decode(
    const float* __restrict__ pred, float* __restrict__ scores,
    int* __restrict__ clsArr, float4* __restrict__ boxes,
    u32* __restrict__ h12) {
  __shared__ __align__(16) float lds[4][1360];
  __shared__ u32 h[4096];
  const int tid = threadIdx.x;
  const int wid = tid >> 6, lane = tid & 63;
  const int q = lane & 3, rl = lane >> 2;
  const int img = blockIdx.y;
  for (int t = tid; t < 4096; t += 256) h[t] = 0;
  float* L = lds[wid];
  const float* base = pred + (size_t)img * NN * NROW;
  const int waveRow0 = blockIdx.x * 256 + wid * 64;
  const int IMGF = NN * NROW;
  __syncthreads();
  for (int c = 0; c < 4; ++c) {
    const int row0 = waveRow0 + c * 16;
    const int fbase = row0 * NROW;
#pragma unroll
    for (int k = 0; k < 5; ++k) {
      int off = k * 256 + lane * 4;
      int src = (fbase + off + 4 <= IMGF) ? (fbase + off) : 0;
      float4 v;
      __builtin_memcpy(&v, base + src, 16);
      *(float4*)(L + off) = v;
    }
    if (lane < 20) {
      int off = 1280 + lane * 4;
      int src = (fbase + off + 4 <= IMGF) ? (fbase + off) : 0;
      float4 v;
      __builtin_memcpy(&v, base + src, 16);
      *(float4*)(L + off) = v;
    }
    __syncthreads();
    const int row = row0 + rl;
    const bool rowOK = (row < NN);
    const float* R = L + rl * 85;
    float obj = R[4];
    float best = -1.0f;
    int bj = 0;
    const int j0 = q * 20;
#pragma unroll
    for (int jj = 0; jj < 20; ++jj) {
      float v = __fmul_rn(R[5 + j0 + jj], obj);
      if (v > best) { best = v; bj = j0 + jj; }
    }
#pragma unroll
    for (int d = 1; d < 4; d <<= 1) {
      float b2 = __shfl_xor(best, d, 64);
      int j2 = __shfl_xor(bj, d, 64);
      if (b2 > best || (b2 == best && j2 < bj)) { best = b2; bj = j2; }
    }
    bool valid = (best > CONF_T);
    if (q == 0 && rowOK) {
      if (valid) atomicAdd(&h[desc_key(best) >> 20], 1u);
      int gid = img * NN + row;
      float x = R[0], y = R[1], w = R[2], hgt = R[3];
      float hx = __fmul_rn(w, 0.5f), hy = __fmul_rn(hgt, 0.5f);
      float4 bx;
      bx.x = __fsub_rn(x, hx);
      bx.y = __fsub_rn(y, hy);
      bx.z = __fadd_rn(x, hx);
      bx.w = __fadd_rn(y, hy);
      scores[gid] = valid ? best : -1.0f;
      clsArr[gid] = bj;
      boxes[gid] = bx;
    }
    __syncthreads();
  }
  u32* hp = h12 + ((size_t)img * HCOPY + (blockIdx.x & (HCOPY - 1))) * 4096;
  for (int t = tid; t < 4096; t += 256) {
    u32 v = h[t];
    if (v) atomicAdd(&hp[t], v);
  }
}

// ------- Kernel 2: monolithic select+NMS (16 blocks, no scratch arrays) -------
__global__ __launch_bounds__(1024) void k_select_nms(
    const float* __restrict__ scores, const int* __restrict__ clsArr,
    const float4* __restrict__ boxes, const u32* __restrict__ h12,
    float* __restrict__ out) {
  const int img = blockIdx.x, tid = threadIdx.x, lane = tid & 63;
  const size_t imgN = (size_t)img * NN;

  extern __shared__ __align__(16) char smem[];
  u64* ck = (u64*)smem;                       // [4096] cands; svKey after NMS
  u64* pk = (u64*)(smem + 32768);             // [1024] participants
  u32* subhist = (u32*)(smem + 32768);        // [256] overlays pk (pre-compact)
  float* lx1 = (float*)(smem + 40960);        // [1024]
  float* ly1 = (float*)(smem + 45056);
  float* lx2 = (float*)(smem + 49152);
  float* ly2 = (float*)(smem + 53248);
  u64* tl = (u64*)(smem + 57344);             // [256] tie list
  u16* svP = (u16*)(smem + 57344);            // overlays tl (post-NMS)
  u8* clsV = (u8*)(smem + 59392);             // [1024]
  u8* aliveF = (u8*)(smem + 60416);           // [1024]
  u32* clsCnt = (u32*)(smem + 61440);         // [80]
  u32* clsStart = (u32*)(smem + 61760);       // [81]
  u16* clsList = (u16*)(smem + 24576);        // [1024] in dead ck tail
  u16* clsSorted = (u16*)(smem + 26624);      // [1024] in dead ck tail
  __shared__ u32 wt[16], wtc[4];
  __shared__ u32 sB, sKr, sThr, sTake, sTie, sP, sSv, sCnt;

  float* outImg = out + (size_t)img * MAXDET * 6;
  for (int t = tid; t < MAXDET * 6; t += 1024) outImg[t] = 0.0f;
  if (tid == 0) {
    sB = 0xFFFFFFFFu; sThr = 0xFFFFFFFFu; sTake = 0x7FFFFFFFu;
    sTie = 0; sP = 0; sSv = 0; sCnt = 0;
  }
  if (tid < NCLS) clsCnt[tid] = 0;
  if (tid < 256) subhist[tid] = 0;

  // ---- A: 12-bit bucket of the 1000th valid key (shfl scan over h12) ----
  const u32* hb = h12 + (size_t)img * HCOPY * 4096;
  uint4 hv = make_uint4(0, 0, 0, 0);
#pragma unroll
  for (int c = 0; c < HCOPY; ++c) {
    uint4 v = *(const uint4*)(hb + c * 4096 + tid * 4);
    hv.x += v.x; hv.y += v.y; hv.z += v.z; hv.w += v.w;
  }
  u32 s4 = hv.x + hv.y + hv.z + hv.w;
  u32 incl = s4;
#pragma unroll
  for (int d = 1; d < 64; d <<= 1) {
    u32 o = __shfl_up(incl, (unsigned)d, 64);
    if (lane >= d) incl += o;
  }
  if (lane == 63) wt[tid >> 6] = incl;
  __syncthreads();
  {
    u32 woff = 0;
    int w = tid >> 6;
    for (int x = 0; x < w; ++x) woff += wt[x];
    u32 P = woff + incl - s4;
    if (P < KPRE && P + s4 >= KPRE) {
      u32 cacc = P, b = 3;
      if (cacc + hv.x >= KPRE) b = 0;
      else {
        cacc += hv.x;
        if (cacc + hv.y >= KPRE) b = 1;
        else {
          cacc += hv.y;
          if (cacc + hv.z >= KPRE) b = 2;
          else cacc += hv.z;
        }
      }
      sB = tid * 4 + b;
      sKr = KPRE - cacc;
    }
  }
  __syncthreads();
  const u32 B = sB;
  const bool noRef = (B == 0xFFFFFFFFu);
  const u32 thr12 = noRef ? 0xFFFu : B;
  const u32 Kr = noRef ? 0x7FFFFFFFu : sKr;

  // ---- G: single streaming pass over scores, gather candidates to LDS ----
  const float* sc = scores + imgN;
  for (int n = tid; n < NN + 1023; n += 1024) {
    bool g = false;
    u32 k = 0;
    if (n < NN) {
      float s = sc[n];
      if (s > CONF_T) {
        k = desc_key(s);
        g = (k >> 20) <= thr12;
      }
    }
    u64 bb = __ballot(g);
    if (bb) {
      int ldr = __ffsll((long long)bb) - 1;
      u32 base = 0;
      if (lane == ldr) base = atomicAdd(&sCnt, (u32)__popcll(bb));
      base = __shfl(base, ldr, 64);
      if (g) {
        u32 pos = base + (u32)__popcll(bb & ((1ull << lane) - 1ull));
        if (pos < CCAP) ck[pos] = ((u64)k << 32) | (u32)n;
      }
    }
  }
  __syncthreads();
  const u32 cnt = sCnt < CCAP ? sCnt : CCAP;

  // ---- R: 8-bit refinement (bits 19..12) over bucket-B candidates ----
  if (!noRef) {
    for (u32 t = tid; t < cnt; t += 1024) {
      u32 key = (u32)(ck[t] >> 32);
      if ((key >> 20) == B) atomicAdd(&subhist[(key >> 12) & 255], 1u);
    }
  }
  __syncthreads();
  {
    u32 myc = (tid < 256) ? subhist[tid] : 0;
    u32 inc2 = myc;
#pragma unroll
    for (int d = 1; d < 64; d <<= 1) {
      u32 o = __shfl_up(inc2, (unsigned)d, 64);
      if (lane >= d) inc2 += o;
    }
    if (tid < 256 && lane == 63) wtc[tid >> 6] = inc2;
    __syncthreads();
    if (!noRef && tid < 256) {
      u32 off = 0;
      int w = tid >> 6;
      for (int x = 0; x < w; ++x) off += wtc[x];
      u32 inc = off + inc2, exc = inc - myc;
      if (exc < Kr && inc >= Kr) {
        sThr = (B << 8) | (u32)tid;  // exact 20-bit threshold
        sTake = Kr - exc;
      }
    }
  }
  __syncthreads();
  const u32 thr20 = sThr, take = sTake;

  // ---- T: tie set at the 20-bit threshold ----
  if (!noRef) {
    for (u32 t = tid; t < cnt; t += 1024) {
      u64 e = ck[t];
      if ((u32)(e >> 44) == thr20) {
        u32 s = atomicAdd(&sTie, 1u);
        if (s < 256) tl[s] = e;
      }
    }
  }
  __syncthreads();
  const u32 tieCnt = sTie;

  // ---- C: keep predicate + compact participants (exactly KPRE normally) ----
  for (u32 t = tid; t < cnt; t += 1024) {
    u64 e = ck[t];
    bool keep;
    if (noRef) {
      keep = true;
    } else {
      u32 p20 = (u32)(e >> 44);
      if (p20 < thr20) keep = true;
      else if (p20 > thr20) keep = false;
      else if (tieCnt <= take) keep = true;
      else {
        u32 tc = tieCnt < 256 ? tieCnt : 256;
        u32 r = 0;
        for (u32 o = 0; o < tc; ++o) r += (tl[o] < e) ? 1u : 0u;
        keep = (r < take);
      }
    }
    if (keep) {
      u32 p = atomicAdd(&sP, 1u);
      if (p < 1024) pk[p] = e;
    }
  }
  __syncthreads();
  const int Pcnt = (int)(sP < 1024 ? sP : 1024);

  // ---- E: fetch cls/box; class counts ----
  int myC = -1;
  u32 arb = 0;
  aliveF[tid] = (tid < Pcnt) ? 1 : 0;
  if (tid < Pcnt) {
    u64 e = pk[tid];
    u32 n = (u32)e;
    int c = clsArr[imgN + n];
    float4 bx = boxes[imgN + n];
    lx1[tid] = bx.x; ly1[tid] = bx.y; lx2[tid] = bx.z; ly2[tid] = bx.w;
    clsV[tid] = (u8)c;
    myC = c;
    arb = atomicAdd(&clsCnt[c], 1u);
  }
  __syncthreads();

  // ---- F: class starts (2-wave scan over 80 counts) ----
  if (tid < 128) {
    u32 v = (tid < NCLS) ? clsCnt[tid] : 0;
    u32 inc = v;
#pragma unroll
    for (int d = 1; d < 64; d <<= 1) {
      u32 o = __shfl_up(inc, (unsigned)d, 64);
      if (lane >= d) inc += o;
    }
    if (lane == 63) wtc[tid >> 6] = inc;
  }
  __syncthreads();
  if (tid < 128) {
    u32 v = (tid < NCLS) ? clsCnt[tid] : 0;
    u32 inc = v;
#pragma unroll
    for (int d = 1; d < 64; d <<= 1) {
      u32 o = __shfl_up(inc, (unsigned)d, 64);
      if (lane >= d) inc += o;
    }
    u32 off = (tid >= 64) ? wtc[0] : 0;
    if (tid <= NCLS) clsStart[tid] = off + inc - v;
    if (tid == NCLS - 1) clsStart[NCLS] = off + inc;
  }
  __syncthreads();
  if (tid < Pcnt) clsList[clsStart[myC] + arb] = (u16)tid;
  __syncthreads();
  if (tid < Pcnt) {
    u32 s = clsStart[myC], e2 = clsStart[myC + 1];
    u64 myk = pk[tid];
    u32 r = 0;
    for (u32 q = s; q < e2; ++q) r += (pk[clsList[q]] < myk) ? 1u : 0u;
    clsSorted[s + r] = (u16)tid;
  }
  __syncthreads();

  // ---- H: per-class sequential greedy NMS (one wave per class) ----
  {
    const int wid2 = tid >> 6;
    for (int c = wid2; c < NCLS; c += 16) {
      int s = (int)clsStart[c], e2 = (int)clsStart[c + 1];
      float offc = __fmul_rn((float)c, 4096.0f);
      for (int i = s; i < e2; ++i) {
        int ti = (int)clsSorted[i];
        if (!aliveF[ti]) continue;  // wave-uniform
        float ix1 = __fadd_rn(lx1[ti], offc), iy1 = __fadd_rn(ly1[ti], offc);
        float ix2 = __fadd_rn(lx2[ti], offc), iy2 = __fadd_rn(ly2[ti], offc);
        float ia = __fmul_rn(__fsub_rn(ix2, ix1), __fsub_rn(iy2, iy1));
        for (int jb = i + 1 + lane; jb < e2; jb += 64) {
          int tj = (int)clsSorted[jb];
          float jx1 = __fadd_rn(lx1[tj], offc), jy1 = __fadd_rn(ly1[tj], offc);
          float jx2 = __fadd_rn(lx2[tj], offc), jy2 = __fadd_rn(ly2[tj], offc);
          float ja = __fmul_rn(__fsub_rn(jx2, jx1), __fsub_rn(jy2, jy1));
          float xx1 = fmaxf(ix1, jx1), yy1 = fmaxf(iy1, jy1);
          float xx2 = fminf(ix2, jx2), yy2 = fminf(iy2, jy2);
          float ww = fmaxf(__fsub_rn(xx2, xx1), 0.0f);
          float hh = fmaxf(__fsub_rn(yy2, yy1), 0.0f);
          float inter = __fmul_rn(ww, hh);
          float den = __fadd_rn(__fsub_rn(__fadd_rn(ia, ja), inter), 1e-9f);
          if (inter > __fmul_rn(IOU_T, den)) aliveF[tj] = 0;
        }
      }
    }
  }
  __syncthreads();

  // ---- S: survivor rank-by-count + output ----
  u64* svKey = ck;  // candidate data dead
  if (tid < Pcnt && aliveF[tid]) {
    u32 s = atomicAdd(&sSv, 1u);
    svKey[s] = pk[tid];
    svP[s] = (u16)tid;
  }
  __syncthreads();
  const u32 S = sSv;
  for (u32 s = tid; s < S; s += 1024) {
    u64 myk = svKey[s];
    u32 r = 0;
    for (u32 o = 0; o < S; ++o) r += (svKey[o] < myk) ? 1u : 0u;
    if (r < MAXDET) {
      int p = (int)svP[s];
      float* o6 = outImg + (size_t)r * 6;
      o6[0] = lx1[p];
      o6[1] = ly1[p];
      o6[2] = lx2[p];
      o6[3] = ly2[p];
      o6[4] = inv_key((u32)(myk >> 32));
      o6[5] = (float)clsV[p];
    }
  }
}

extern "C" void kernel_launch(void* const* d_in, const int* in_sizes, int n_in,
                              void* d_out, int out_size, void* d_ws, size_t ws_size,
                              hipStream_t stream) {
  const float* pred = (const float*)d_in[0];
  char* ws = (char*)d_ws;
  size_t off = 0;
  float* scores = (float*)(ws + off); off += (size_t)NB * NN * 4;
  int* clsArr = (int*)(ws + off); off += (size_t)NB * NN * 4;
  float4* boxes = (float4*)(ws + off); off += (size_t)NB * NN * 16;
  u32* h12 = (u32*)(ws + off); off += (size_t)NB * HCOPY * 4096 * 4;
  if (off > ws_size) return;

  const int TOTZ = NB * HCOPY * 4096;
  float* outp = (float*)d_out;
  k_zero<<<(TOTZ + 1023) / 1024, 1024, 0, stream>>>(h12, TOTZ);
  dim3 gridD((NN + 255) / 256, NB);
  k_decode<<<gridD, 256, 0, stream>>>(pred, scores, clsArr, boxes, h12);
  k_select_nms<<<NB, 1024, 62208, stream>>>(scores, clsArr, boxes, h12, outp);
}

// Round 13
// 108.765 us; speedup vs baseline: 1.8100x; 1.0057x over previous
//
#include <hip/hip_runtime.h>
#include <stdint.h>

#define NB 16
#define NN 25200
#define NCLS 80
#define NROW 85
#define KPRE 1000
#define MAXDET 300
#define CONF_T 0.25f
#define IOU_T 0.45f
#define CCAP 4096  // candidate capacity (LDS)

typedef unsigned long long u64;
typedef unsigned int u32;
typedef unsigned short u16;
typedef unsigned char u8;

// Descending-order sortable key: higher score -> smaller key; ties by index.
__device__ __forceinline__ u32 desc_key(float s) {
  u32 u = __float_as_uint(s);
  u = (u & 0x80000000u) ? ~u : (u | 0x80000000u);
  return ~u;
}
__device__ __forceinline__ float inv_key(u32 k) {
  u32 u = ~k;
  u32 o = (u & 0x80000000u) ? (u & 0x7fffffffu) : ~u;
  return __uint_as_float(o);
}

// ---------------- Kernel 0: zero h12 region (256 KB) ----------------
__global__ __launch_bounds__(1024) void k_zero(u32* __restrict__ z) {
  z[blockIdx.x * 1024 + threadIdx.x] = 0;
}

// ------- Kernel 1: decode (LDS-staged coalesced) + fused 12-bit hist -------
__global__ __launch_bounds__(256) void k_decode(
    const float* __restrict__ pred, float* __restrict__ scores,
    int* __restrict__ clsArr, float4* __restrict__ boxes,
    u32* __restrict__ h12) {
  __shared__ __align__(16) float lds[4][1360];
  __shared__ u32 h[4096];
  const int tid = threadIdx.x;
  const int wid = tid >> 6, lane = tid & 63;
  const int q = lane & 3, rl = lane >> 2;
  const int img = blockIdx.y;
  for (int t = tid; t < 4096; t += 256) h[t] = 0;
  float* L = lds[wid];
  const float* base = pred + (size_t)img * NN * NROW;
  const int waveRow0 = blockIdx.x * 256 + wid * 64;
  const int IMGF = NN * NROW;
  __syncthreads();
  for (int c = 0; c < 4; ++c) {
    const int row0 = waveRow0 + c * 16;
    const int fbase = row0 * NROW;
#pragma unroll
    for (int k = 0; k < 5; ++k) {
      int off = k * 256 + lane * 4;
      int src = (fbase + off + 4 <= IMGF) ? (fbase + off) : 0;
      float4 v;
      __builtin_memcpy(&v, base + src, 16);
      *(float4*)(L + off) = v;
    }
    if (lane < 20) {
      int off = 1280 + lane * 4;
      int src = (fbase + off + 4 <= IMGF) ? (fbase + off) : 0;
      float4 v;
      __builtin_memcpy(&v, base + src, 16);
      *(float4*)(L + off) = v;
    }
    __syncthreads();
    const int row = row0 + rl;
    const bool rowOK = (row < NN);
    const float* R = L + rl * 85;
    float obj = R[4];
    float best = -1.0f;
    int bj = 0;
    const int j0 = q * 20;
#pragma unroll
    for (int jj = 0; jj < 20; ++jj) {
      float v = __fmul_rn(R[5 + j0 + jj], obj);
      if (v > best) { best = v; bj = j0 + jj; }
    }
#pragma unroll
    for (int d = 1; d < 4; d <<= 1) {
      float b2 = __shfl_xor(best, d, 64);
      int j2 = __shfl_xor(bj, d, 64);
      if (b2 > best || (b2 == best && j2 < bj)) { best = b2; bj = j2; }
    }
    bool valid = (best > CONF_T);
    if (q == 0 && rowOK) {
      if (valid) atomicAdd(&h[desc_key(best) >> 20], 1u);
      int gid = img * NN + row;
      float x = R[0], y = R[1], w = R[2], hgt = R[3];
      float hx = __fmul_rn(w, 0.5f), hy = __fmul_rn(hgt, 0.5f);
      float4 bx;
      bx.x = __fsub_rn(x, hx);
      bx.y = __fsub_rn(y, hy);
      bx.z = __fadd_rn(x, hx);
      bx.w = __fadd_rn(y, hy);
      scores[gid] = valid ? best : -1.0f;
      clsArr[gid] = bj;
      boxes[gid] = bx;
    }
    __syncthreads();
  }
  u32* hp = h12 + (size_t)img * 4096;
  for (int t = tid; t < 4096; t += 256) {
    u32 v = h[t];
    if (v) atomicAdd(&hp[t], v);
  }
}

// ------- Kernel 2: monolithic select+NMS (16 blocks) -------
__global__ __launch_bounds__(1024) void k_select_nms(
    const float* __restrict__ scores, const int* __restrict__ clsArr,
    const float4* __restrict__ boxes, const u32* __restrict__ h12,
    float* __restrict__ out) {
  const int img = blockIdx.x, tid = threadIdx.x, lane = tid & 63;
  const size_t imgN = (size_t)img * NN;

  extern __shared__ __align__(16) char smem[];
  u64* ck = (u64*)smem;                       // [4096] cands; svKey after NMS
  u64* pk = (u64*)(smem + 32768);             // [1024] participants
  u32* subhist = (u32*)(smem + 32768);        // [256] overlays pk (pre-compact)
  float* lx1 = (float*)(smem + 40960);        // [1024]
  float* ly1 = (float*)(smem + 45056);
  float* lx2 = (float*)(smem + 49152);
  float* ly2 = (float*)(smem + 53248);
  u64* tl = (u64*)(smem + 57344);             // [256] tie list
  u16* svP = (u16*)(smem + 57344);            // overlays tl (post-NMS)
  u8* clsV = (u8*)(smem + 59392);             // [1024]
  u8* aliveF = (u8*)(smem + 60416);           // [1024]
  u32* clsCnt = (u32*)(smem + 61440);         // [80]
  u32* clsStart = (u32*)(smem + 61760);       // [81]
  u16* clsList = (u16*)(smem + 24576);        // [1024] in dead ck tail
  u16* clsSorted = (u16*)(smem + 26624);      // [1024] in dead ck tail
  __shared__ u32 wt[16], wtc[4];
  __shared__ u32 sB, sKr, sThr, sTake, sTie, sP, sSv, sCnt;

  float* outImg = out + (size_t)img * MAXDET * 6;
  for (int t = tid; t < MAXDET * 6; t += 1024) outImg[t] = 0.0f;
  if (tid == 0) {
    sB = 0xFFFFFFFFu; sThr = 0xFFFFFFFFu; sTake = 0x7FFFFFFFu;
    sTie = 0; sP = 0; sSv = 0; sCnt = 0;
  }
  if (tid < NCLS) clsCnt[tid] = 0;
  if (tid < 256) subhist[tid] = 0;

  // ---- A: 12-bit bucket of the 1000th valid key (shfl scan over h12) ----
  uint4 hv = *(const uint4*)(h12 + (size_t)img * 4096 + tid * 4);
  u32 s4 = hv.x + hv.y + hv.z + hv.w;
  u32 incl = s4;
#pragma unroll
  for (int d = 1; d < 64; d <<= 1) {
    u32 o = __shfl_up(incl, (unsigned)d, 64);
    if (lane >= d) incl += o;
  }
  if (lane == 63) wt[tid >> 6] = incl;
  __syncthreads();
  {
    u32 woff = 0;
    int w = tid >> 6;
    for (int x = 0; x < w; ++x) woff += wt[x];
    u32 P = woff + incl - s4;
    if (P < KPRE && P + s4 >= KPRE) {
      u32 cacc = P, b = 3;
      if (cacc + hv.x >= KPRE) b = 0;
      else {
        cacc += hv.x;
        if (cacc + hv.y >= KPRE) b = 1;
        else {
          cacc += hv.y;
          if (cacc + hv.z >= KPRE) b = 2;
          else cacc += hv.z;
        }
      }
      sB = tid * 4 + b;
      sKr = KPRE - cacc;
    }
  }
  __syncthreads();
  const u32 B = sB;
  const bool noRef = (B == 0xFFFFFFFFu);
  const u32 thr12 = noRef ? 0xFFFu : B;
  const u32 Kr = noRef ? 0x7FFFFFFFu : sKr;

  // ---- G: single streaming pass over scores, gather candidates to LDS ----
  const float* sc = scores + imgN;
  for (int n = tid; n < NN + 1023; n += 1024) {
    bool g = false;
    u32 k = 0;
    if (n < NN) {
      float s = sc[n];
      if (s > CONF_T) {
        k = desc_key(s);
        g = (k >> 20) <= thr12;
      }
    }
    u64 bb = __ballot(g);
    if (bb) {
      int ldr = __ffsll((long long)bb) - 1;
      u32 base = 0;
      if (lane == ldr) base = atomicAdd(&sCnt, (u32)__popcll(bb));
      base = __shfl(base, ldr, 64);
      if (g) {
        u32 pos = base + (u32)__popcll(bb & ((1ull << lane) - 1ull));
        if (pos < CCAP) ck[pos] = ((u64)k << 32) | (u32)n;
      }
    }
  }
  __syncthreads();
  const u32 cnt = sCnt < CCAP ? sCnt : CCAP;

  // ---- R: 8-bit refinement (bits 19..12) over bucket-B candidates ----
  if (!noRef) {
    for (u32 t = tid; t < cnt; t += 1024) {
      u32 key = (u32)(ck[t] >> 32);
      if ((key >> 20) == B) atomicAdd(&subhist[(key >> 12) & 255], 1u);
    }
  }
  __syncthreads();
  {
    u32 myc = (tid < 256) ? subhist[tid] : 0;
    u32 inc2 = myc;
#pragma unroll
    for (int d = 1; d < 64; d <<= 1) {
      u32 o = __shfl_up(inc2, (unsigned)d, 64);
      if (lane >= d) inc2 += o;
    }
    if (tid < 256 && lane == 63) wtc[tid >> 6] = inc2;
    __syncthreads();
    if (!noRef && tid < 256) {
      u32 off = 0;
      int w = tid >> 6;
      for (int x = 0; x < w; ++x) off += wtc[x];
      u32 inc = off + inc2, exc = inc - myc;
      if (exc < Kr && inc >= Kr) {
        sThr = (B << 8) | (u32)tid;  // exact 20-bit threshold
        sTake = Kr - exc;
      }
    }
  }
  __syncthreads();
  const u32 thr20 = sThr, take = sTake;

  // ---- T: tie set at the 20-bit threshold ----
  if (!noRef) {
    for (u32 t = tid; t < cnt; t += 1024) {
      u64 e = ck[t];
      if ((u32)(e >> 44) == thr20) {
        u32 s = atomicAdd(&sTie, 1u);
        if (s < 256) tl[s] = e;
      }
    }
  }
  __syncthreads();
  const u32 tieCnt = sTie;

  // ---- C: keep predicate + compact participants (exactly KPRE normally) ----
  for (u32 t = tid; t < cnt; t += 1024) {
    u64 e = ck[t];
    bool keep;
    if (noRef) {
      keep = true;
    } else {
      u32 p20 = (u32)(e >> 44);
      if (p20 < thr20) keep = true;
      else if (p20 > thr20) keep = false;
      else if (tieCnt <= take) keep = true;
      else {
        u32 tc = tieCnt < 256 ? tieCnt : 256;
        u32 r = 0;
        for (u32 o = 0; o < tc; ++o) r += (tl[o] < e) ? 1u : 0u;
        keep = (r < take);
      }
    }
    if (keep) {
      u32 p = atomicAdd(&sP, 1u);
      if (p < 1024) pk[p] = e;
    }
  }
  __syncthreads();
  const int Pcnt = (int)(sP < 1024 ? sP : 1024);

  // ---- E: fetch cls/box; class counts ----
  int myC = -1;
  u32 arb = 0;
  aliveF[tid] = (tid < Pcnt) ? 1 : 0;
  if (tid < Pcnt) {
    u64 e = pk[tid];
    u32 n = (u32)e;
    int c = clsArr[imgN + n];
    float4 bx = boxes[imgN + n];
    lx1[tid] = bx.x; ly1[tid] = bx.y; lx2[tid] = bx.z; ly2[tid] = bx.w;
    clsV[tid] = (u8)c;
    myC = c;
    arb = atomicAdd(&clsCnt[c], 1u);
  }
  __syncthreads();

  // ---- F: class starts (2-wave scan over 80 counts) ----
  if (tid < 128) {
    u32 v = (tid < NCLS) ? clsCnt[tid] : 0;
    u32 inc = v;
#pragma unroll
    for (int d = 1; d < 64; d <<= 1) {
      u32 o = __shfl_up(inc, (unsigned)d, 64);
      if (lane >= d) inc += o;
    }
    if (lane == 63) wtc[tid >> 6] = inc;
  }
  __syncthreads();
  if (tid < 128) {
    u32 v = (tid < NCLS) ? clsCnt[tid] : 0;
    u32 inc = v;
#pragma unroll
    for (int d = 1; d < 64; d <<= 1) {
      u32 o = __shfl_up(inc, (unsigned)d, 64);
      if (lane >= d) inc += o;
    }
    u32 off = (tid >= 64) ? wtc[0] : 0;
    if (tid <= NCLS) clsStart[tid] = off + inc - v;
    if (tid == NCLS - 1) clsStart[NCLS] = off + inc;
  }
  __syncthreads();
  if (tid < Pcnt) clsList[clsStart[myC] + arb] = (u16)tid;
  __syncthreads();
  if (tid < Pcnt) {
    u32 s = clsStart[myC], e2 = clsStart[myC + 1];
    u64 myk = pk[tid];
    u32 r = 0;
    for (u32 q = s; q < e2; ++q) r += (pk[clsList[q]] < myk) ? 1u : 0u;
    clsSorted[s + r] = (u16)tid;
  }
  __syncthreads();

  // ---- H: per-class sequential greedy NMS (one wave per class) ----
  {
    const int wid2 = tid >> 6;
    for (int c = wid2; c < NCLS; c += 16) {
      int s = (int)clsStart[c], e2 = (int)clsStart[c + 1];
      float offc = __fmul_rn((float)c, 4096.0f);
      for (int i = s; i < e2; ++i) {
        int ti = (int)clsSorted[i];
        if (!aliveF[ti]) continue;  // wave-uniform
        float ix1 = __fadd_rn(lx1[ti], offc), iy1 = __fadd_rn(ly1[ti], offc);
        float ix2 = __fadd_rn(lx2[ti], offc), iy2 = __fadd_rn(ly2[ti], offc);
        float ia = __fmul_rn(__fsub_rn(ix2, ix1), __fsub_rn(iy2, iy1));
        for (int jb = i + 1 + lane; jb < e2; jb += 64) {
          int tj = (int)clsSorted[jb];
          float jx1 = __fadd_rn(lx1[tj], offc), jy1 = __fadd_rn(ly1[tj], offc);
          float jx2 = __fadd_rn(lx2[tj], offc), jy2 = __fadd_rn(ly2[tj], offc);
          float ja = __fmul_rn(__fsub_rn(jx2, jx1), __fsub_rn(jy2, jy1));
          float xx1 = fmaxf(ix1, jx1), yy1 = fmaxf(iy1, jy1);
          float xx2 = fminf(ix2, jx2), yy2 = fminf(iy2, jy2);
          float ww = fmaxf(__fsub_rn(xx2, xx1), 0.0f);
          float hh = fmaxf(__fsub_rn(yy2, yy1), 0.0f);
          float inter = __fmul_rn(ww, hh);
          float den = __fadd_rn(__fsub_rn(__fadd_rn(ia, ja), inter), 1e-9f);
          if (inter > __fmul_rn(IOU_T, den)) aliveF[tj] = 0;
        }
      }
    }
  }
  __syncthreads();

  // ---- S: survivor rank-by-count + output ----
  u64* svKey = ck;  // candidate data dead
  if (tid < Pcnt && aliveF[tid]) {
    u32 s = atomicAdd(&sSv, 1u);
    svKey[s] = pk[tid];
    svP[s] = (u16)tid;
  }
  __syncthreads();
  const u32 S = sSv;
  for (u32 s = tid; s < S; s += 1024) {
    u64 myk = svKey[s];
    u32 r = 0;
    for (u32 o = 0; o < S; ++o) r += (svKey[o] < myk) ? 1u : 0u;
    if (r < MAXDET) {
      int p = (int)svP[s];
      float* o6 = outImg + (size_t)r * 6;
      o6[0] = lx1[p];
      o6[1] = ly1[p];
      o6[2] = lx2[p];
      o6[3] = ly2[p];
      o6[4] = inv_key((u32)(myk >> 32));
      o6[5] = (float)clsV[p];
    }
  }
}

extern "C" void kernel_launch(void* const* d_in, const int* in_sizes, int n_in,
                              void* d_out, int out_size, void* d_ws, size_t ws_size,
                              hipStream_t stream) {
  const float* pred = (const float*)d_in[0];
  char* ws = (char*)d_ws;
  size_t off = 0;
  float* scores = (float*)(ws + off); off += (size_t)NB * NN * 4;
  int* clsArr = (int*)(ws + off); off += (size_t)NB * NN * 4;
  float4* boxes = (float4*)(ws + off); off += (size_t)NB * NN * 16;
  u32* h12 = (u32*)(ws + off); off += (size_t)NB * 4096 * 4;
  if (off > ws_size) return;

  float* outp = (float*)d_out;
  k_zero<<<NB * 4096 / 1024, 1024, 0, stream>>>(h12);
  dim3 gridD((NN + 255) / 256, NB);
  k_decode<<<gridD, 256, 0, stream>>>(pred, scores, clsArr, boxes, h12);
  k_select_nms<<<NB, 1024, 62208, stream>>>(scores, clsArr, boxes, h12, outp);
}